// Round 15
// baseline (2015.399 us; speedup 1.0000x reference)
//
#include <hip/hip_runtime.h>
#include <hip/hip_fp16.h>

#define B_ 128
#define T_ 64
#define I_ 128
#define H_ 256
#define UF 6
#define EPSF 1e-8f

typedef _Float16 f16x2 __attribute__((ext_vector_type(2)));
union H2U { __half2 h; f16x2 v; unsigned u; };

static __device__ __forceinline__ float rcpf(float x) { return __builtin_amdgcn_rcpf(x); }
static __device__ __forceinline__ unsigned f2h(float f) { return (unsigned)__half_as_ushort(__float2half_rn(f)); }

// packed-fp16 dual gate: 2 sigmoids + f32 dot-accumulate into NM/DN (proven R7)
#define GATE2(VW, AK, BK, WK, NM, DN) {                        \
    H2U v2_; v2_.u = (VW);                                     \
    H2U av_; av_.u = (AK);                                     \
    H2U bv_; bv_.u = (BK);                                     \
    __half2 z_ = __hfma2(av_.h, v2_.h, bv_.h);                 \
    __half2 e_ = h2exp2(z_);                                   \
    __half2 s_ = __hadd2(e_, __float2half2_rn(1.0f));          \
    H2U rv_; rv_.h = h2rcp(s_);                                \
    H2U ws_; ws_.u = (WK);                                     \
    H2U wa_; wa_.u = ws_.u & 0x7fff7fffu;                      \
    NM = __builtin_amdgcn_fdot2(ws_.v, rv_.v, NM, false);      \
    DN = __builtin_amdgcn_fdot2(wa_.v, rv_.v, DN, false);      \
}

// ---------------- K0: pack params (A = -sig*L2E, B = sig*mu*L2E, W = w*erev).
// Internal AB: ABq[q][pp][jcol] uint2 — per-quarter, quarter-ROTATED so a block's
//   k=0,1 pairs are always its own quarter: pp = k*16 + c encodes pair
//   ip = 32*((q + (k>>1))&3) + 16*(k&1) + c, column jcol = j ^ ((pp&7)<<3)
//   (bank swizzle: <=2-way conflict on ds_read_b64).
// Internal W: Wg[P][jg] plain pair index. Sensing: SAB/SW [p][jg].
// Zero exchange tags every launch.
__global__ __launch_bounds__(256) void pack_params(
    const float* __restrict__ smu, const float* __restrict__ ssig,
    const float* __restrict__ sw,  const float* __restrict__ serev,
    const float* __restrict__ imu, const float* __restrict__ isig,
    const float* __restrict__ iw,  const float* __restrict__ ierev,
    uint2* __restrict__ ABq, unsigned* __restrict__ Wg,
    uint2* __restrict__ SABg, unsigned* __restrict__ SWg,
    unsigned* __restrict__ Vg4)
{
    const float K = 1.4426950408889634f;
    int idx = blockIdx.x * 256 + threadIdx.x;     // [0, 32768)
    {   // internal AB, rotated + swizzled
        int q = idx >> 13, pp = (idx >> 6) & 127, jcol = idx & 63;
        int k = pp >> 4, c = pp & 15;
        int ip = (((q + (k >> 1)) & 3) << 5) + ((k & 1) << 4) + c;
        int j = jcol ^ ((pp & 7) << 3);
        int jg = (q << 6) + j;
        int i0 = 2 * ip, i1 = i0 + 1;
        unsigned a0 = f2h(-isig[i0 * H_ + jg] * K);
        unsigned a1 = f2h(-isig[i1 * H_ + jg] * K);
        unsigned b0 = f2h(isig[i0 * H_ + jg] * imu[i0 * H_ + jg] * K);
        unsigned b1 = f2h(isig[i1 * H_ + jg] * imu[i1 * H_ + jg] * K);
        ABq[idx] = make_uint2(a0 | (a1 << 16), b0 | (b1 << 16));
    }
    {   // internal W [P][jg]
        int P = idx >> 8, jg = idx & 255;
        int i0 = 2 * P, i1 = i0 + 1;
        unsigned w0 = f2h(iw[i0 * H_ + jg] * ierev[i0 * H_ + jg]);
        unsigned w1 = f2h(iw[i1 * H_ + jg] * ierev[i1 * H_ + jg]);
        Wg[idx] = w0 | (w1 << 16);
    }
    if (idx < 64 * H_) {   // sensing [p][jg]
        int p = idx >> 8, jg = idx & 255;
        int i0 = 2 * p, i1 = i0 + 1;
        unsigned a0 = f2h(-ssig[i0 * H_ + jg] * K);
        unsigned a1 = f2h(-ssig[i1 * H_ + jg] * K);
        unsigned b0 = f2h(ssig[i0 * H_ + jg] * smu[i0 * H_ + jg] * K);
        unsigned b1 = f2h(ssig[i1 * H_ + jg] * smu[i1 * H_ + jg] * K);
        SABg[idx] = make_uint2(a0 | (a1 << 16), b0 | (b1 << 16));
        unsigned w0 = f2h(sw[i0 * H_ + jg] * serev[i0 * H_ + jg]);
        unsigned w1 = f2h(sw[i1 * H_ + jg] * serev[i1 * H_ + jg]);
        SWg[idx] = w0 | (w1 << 16);
    }
    Vg4[idx] = 0u;
    Vg4[idx + 32768] = 0u;
}

// ---------------- K1: recurrent LTC, 4-way j-split for 2 blocks/CU occupancy.
// 512 blocks x 1024 threads: block (b = bx&127, quarter q = bx>>7) owns 64
// neurons. LDS = 64KB AB + 0.7KB -> exactly 2 blocks/CU, 32 waves/CU
// (8/SIMD, 2x R7) — one block's barrier drain hides under the other's gates.
// All 512 blocks co-resident by construction (threads 2x1024=2048/CU max,
// VGPR<=64 pinned by waves_per_eu(8,8)) -> tagged-word spin is deadlock-safe
// (same monotone-tag proof as R7, extended to 3 peers).
// Lane map tid = j*16 + c; reduce over c via 4 shfl_xor. Pair order rotated so
// k=0,1 = own quarter (static phase A), k=2..7 = peers (phase B).
// Poll: waves 0-2, 1 per-lane tagged word each (R7's proven pattern).
__global__ __launch_bounds__(1024)
__attribute__((amdgpu_waves_per_eu(8, 8)))
void ltc_rec(
    const float* __restrict__ x, const float* __restrict__ in_w, const float* __restrict__ in_b,
    const uint2* __restrict__ ABq, const unsigned* __restrict__ Wg,
    const uint2* __restrict__ SABg, const unsigned* __restrict__ SWg,
    const float* __restrict__ vleak, const float* __restrict__ gleak, const float* __restrict__ cm,
    const float* __restrict__ out_w, const float* __restrict__ out_b,
    unsigned* __restrict__ Vg4,
    float* __restrict__ out, float* __restrict__ hT)
{
    // LDS: [0, 65536) AB | V2u 128 words (512 B) | xs2 64 words (256 B)
    __shared__ __align__(16) unsigned char L[66304];
    unsigned* V2u = (unsigned*)(L + 65536);
    unsigned* xs2 = (unsigned*)(L + 66048);

    const int bx  = blockIdx.x;
    const int b   = bx & 127;
    const int q   = bx >> 7;             // own j-quarter
    const int tid = threadIdx.x;
    const int c   = tid & 15;            // i-chunk (low bits -> in-wave reduce)
    const int j   = tid >> 4;            // 0..63 local neuron
    const int jg  = (q << 6) + j;
    const int wv  = tid >> 6;            // wave 0..15
    const int Ln  = tid & 63;
    const int BH  = B_ * H_;

    // stage own-quarter AB (pre-rotated, pre-swizzled) into LDS: 64 KB
    {
        const uint4* src = (const uint4*)(ABq + ((size_t)q << 13));
        uint4* dst = (uint4*)L;
        #pragma unroll
        for (int k = 0; k < 4; ++k) dst[tid + (k << 10)] = src[tid + (k << 10)];
    }

    // W registers: 8 pairs, rotated order matching AB
    unsigned rw[8];
    #pragma unroll
    for (int k = 0; k < 8; ++k) {
        int ip = (((q + (k >> 1)) & 3) << 5) + ((k & 1) << 4) + c;
        rw[k] = Wg[(ip << 8) + jg];
    }

    const float cmt  = cm[jg] * (float)UF;
    const float gl   = gleak[jg];
    const float glvl = gl * vleak[jg];
    const float dc   = cmt + gl + EPSF;
    const float owj  = out_w[jg], obj = out_b[jg];
    float iw0 = 0.f, iw1 = 0.f, ib0 = 0.f, ib1 = 0.f;
    if (tid < 64) { iw0 = in_w[2 * tid]; iw1 = in_w[2 * tid + 1];
                    ib0 = in_b[2 * tid]; ib1 = in_b[2 * tid + 1]; }
    if (tid < 128) V2u[tid] = 0u;
    float vreg = 0.f;

    const float* xrow = x + (size_t)b * (T_ * I_);

    // per-thread bases
    const char* abBase = (const char*)L + (c << 9) + ((j ^ ((c & 7) << 3)) << 3);
    int vq[4];
    #pragma unroll
    for (int d = 0; d < 4; ++d) vq[d] = (((q + d) & 3) << 5) + c;   // V2u word base per quarter
    const uint2* sabBase = SABg + ((c << 2) << 8) + jg;
    const unsigned* swBase = SWg + ((c << 2) << 8) + jg;

    for (int t = 0; t < T_; ++t) {
        if (tid < 64) {
            float2 xv = *(const float2*)(xrow + t * I_ + 2 * tid);
            H2U u_; u_.h = __floats2half2_rn(fmaf(xv.x, iw0, ib0), fmaf(xv.y, iw1, ib1));
            xs2[tid] = u_.u;
        }
        __syncthreads();   // xs2 ready (covers AB/V2u init at t==0)

        // ---- sensing partials: 4 GATE2, params streamed from L2, reused 6 unfolds
        float qsn = 0.f, qsd = 0.f;
        #pragma unroll
        for (int m = 0; m < 4; ++m) {
            uint2 sab = sabBase[m << 8];
            unsigned swv = swBase[m << 8];
            unsigned xw = xs2[(c << 2) + m];
            GATE2(xw, sab.x, sab.y, swv, qsn, qsd);
        }

        for (int u = 0; u < UF; ++u) {
            const int p = t * UF + u + 1;
            float nm = qsn, dn = qsd;

            // ---- prefetch peer tagged words: waves 0-2, 1 per-lane word each
            unsigned pv = 0, want = 0; const unsigned* srcp = nullptr; int pjg = 0;
            const bool mine = (wv < 3);
            if (p > 1 && mine) {
                want = (unsigned)(p - 1);
                pjg = (((q + 1 + wv) & 3) << 6) + Ln;
                srcp = Vg4 + (size_t)(want & 1) * BH + (b << 8) + pjg;
                pv = __hip_atomic_load(srcp, __ATOMIC_RELAXED, __HIP_MEMORY_SCOPE_AGENT);
            }

            // ---- phase A: own-quarter pairs (k = 0,1), V2u locally fresh
            #pragma unroll
            for (int k = 0; k < 2; ++k) {
                unsigned vw = V2u[vq[0] + ((k & 1) << 4)];
                uint2 ab = *(const uint2*)(abBase + (k << 13));
                GATE2(vw, ab.x, ab.y, rw[k], nm, dn);
            }

            // ---- finish poll, write peer V2u pairs
            if (p > 1 && mine) {
                while ((pv >> 16) != want)
                    pv = __hip_atomic_load(srcp, __ATOMIC_RELAXED, __HIP_MEMORY_SCOPE_AGENT);
                unsigned hv = pv & 0xffffu;
                unsigned hv1 = (unsigned)__shfl_down((int)hv, 1);
                if (!(Ln & 1)) V2u[pjg >> 1] = hv | (hv1 << 16);
            }
            __syncthreads();   // barrier-a: peer V2u ready

            // ---- phase B: peer-quarter pairs (k = 2..7)
            #pragma unroll
            for (int k = 2; k < 8; ++k) {
                unsigned vw = V2u[vq[k >> 1] + ((k & 1) << 4)];
                uint2 ab = *(const uint2*)(abBase + (k << 13));
                GATE2(vw, ab.x, ab.y, rw[k], nm, dn);
            }

            // ---- in-wave reduce over c (16 lanes per neuron)
            nm += __shfl_xor(nm, 1); dn += __shfl_xor(dn, 1);
            nm += __shfl_xor(nm, 2); dn += __shfl_xor(dn, 2);
            nm += __shfl_xor(nm, 4); dn += __shfl_xor(dn, 4);
            nm += __shfl_xor(nm, 8); dn += __shfl_xor(dn, 8);

            // ---- update (all lanes), publish tagged word + own V2u write (c==0)
            float Vn = (fmaf(vreg, cmt, glvl) + nm) * rcpf(dn + dc);
            vreg = Vn;
            unsigned h0 = (unsigned)__half_as_ushort(__float2half_rn(Vn));
            if (c == 0)
                __hip_atomic_store(Vg4 + (size_t)(p & 1) * BH + (b << 8) + jg,
                                   ((unsigned)p << 16) | h0,
                                   __ATOMIC_RELAXED, __HIP_MEMORY_SCOPE_AGENT);
            unsigned h1 = (unsigned)__shfl_down((int)h0, 16);
            if (c == 0 && !(j & 1)) V2u[jg >> 1] = h0 | (h1 << 16);
            __syncthreads();   // barrier-b: own V2u ready for next phase A
        }

        if (c == 0) out[((size_t)b * T_ + t) * H_ + jg] = fmaf(vreg, owj, obj);
    }
    if (c == 0) hT[(b << 8) + jg] = vreg;
}

extern "C" void kernel_launch(void* const* d_in, const int* in_sizes, int n_in,
                              void* d_out, int out_size, void* d_ws, size_t ws_size,
                              hipStream_t stream) {
    const float* x     = (const float*)d_in[0];
    const float* in_w  = (const float*)d_in[1];
    const float* in_b  = (const float*)d_in[2];
    const float* smu   = (const float*)d_in[3];
    const float* ssig  = (const float*)d_in[4];
    const float* sw    = (const float*)d_in[5];
    const float* serev = (const float*)d_in[6];
    const float* imu   = (const float*)d_in[7];
    const float* isig  = (const float*)d_in[8];
    const float* iw    = (const float*)d_in[9];
    const float* ierev = (const float*)d_in[10];
    const float* vleak = (const float*)d_in[11];
    const float* gleak = (const float*)d_in[12];
    const float* cmv   = (const float*)d_in[13];
    const float* ow    = (const float*)d_in[14];
    const float* ob    = (const float*)d_in[15];

    float* out = (float*)d_out;                 // [B, T, H]
    float* hT  = out + (size_t)B_ * T_ * H_;    // [B, H]

    char* w = (char*)d_ws;
    uint2*    ABq  = (uint2*)(w);                    // 256 KB [q][pp][jcol]
    unsigned* Wg   = (unsigned*)(w + (256 << 10));   // 128 KB [P][jg]
    uint2*    SABg = (uint2*)(w + (384 << 10));      // 128 KB [p][jg]
    unsigned* SWg  = (unsigned*)(w + (512 << 10));   //  64 KB [p][jg]
    unsigned* Vg4  = (unsigned*)(w + (576 << 10));   // 256 KB [2][B][H] tag|fp16

    pack_params<<<dim3(128), dim3(256), 0, stream>>>(
        smu, ssig, sw, serev, imu, isig, iw, ierev, ABq, Wg, SABg, SWg, Vg4);

    ltc_rec<<<dim3(512), dim3(1024), 0, stream>>>(
        x, in_w, in_b, ABq, Wg, SABg, SWg, vleak, gleak, cmv, ow, ob,
        Vg4, out, hT);
}

// Round 16
// 970.851 us; speedup vs baseline: 2.0759x; 2.0759x over previous
//
#include <hip/hip_runtime.h>
#include <hip/hip_fp16.h>

#define B_ 128
#define T_ 64
#define I_ 128
#define H_ 256
#define UF 6
#define EPSF 1e-8f

typedef _Float16 f16x2 __attribute__((ext_vector_type(2)));
union H2U { __half2 h; f16x2 v; unsigned u; };

static __device__ __forceinline__ float rcpf(float x) { return __builtin_amdgcn_rcpf(x); }
static __device__ __forceinline__ unsigned f2h(float f) { return (unsigned)__half_as_ushort(__float2half_rn(f)); }

// packed-fp16 dual gate: 2 sigmoids + f32 dot-accumulate into NM/DN
#define GATE2(VW, AK, BK, WK, NM, DN) {                        \
    H2U v2_; v2_.u = (VW);                                     \
    H2U av_; av_.u = (AK);                                     \
    H2U bv_; bv_.u = (BK);                                     \
    __half2 z_ = __hfma2(av_.h, v2_.h, bv_.h);                 \
    __half2 e_ = h2exp2(z_);                                   \
    __half2 s_ = __hadd2(e_, __float2half2_rn(1.0f));          \
    H2U rv_; rv_.h = h2rcp(s_);                                \
    H2U ws_; ws_.u = (WK);                                     \
    H2U wa_; wa_.u = ws_.u & 0x7fff7fffu;                      \
    NM = __builtin_amdgcn_fdot2(ws_.v, rv_.v, NM, false);      \
    DN = __builtin_amdgcn_fdot2(wa_.v, rv_.v, DN, false);      \
}

// ---------------- K0: pack params (A = -sig*L2E, B = sig*mu*L2E, W = w*erev).
// Internal AB: bank-swizzled [jh][P][jcol] uint2, jcol = j ^ 2*((P>>3)&7).
// Internal W:  [P][jg] packed pairs. Sensing: SAB [p][jg] uint2, SW [p][jg].
// Zero the exchange tags (both buffers) every launch.
__global__ __launch_bounds__(256) void pack_params(
    const float* __restrict__ smu, const float* __restrict__ ssig,
    const float* __restrict__ sw,  const float* __restrict__ serev,
    const float* __restrict__ imu, const float* __restrict__ isig,
    const float* __restrict__ iw,  const float* __restrict__ ierev,
    uint2* __restrict__ ABg, unsigned* __restrict__ Wg,
    uint2* __restrict__ SABg, unsigned* __restrict__ SWg,
    unsigned* __restrict__ Vg4)
{
    const float K = 1.4426950408889634f;
    int idx = blockIdx.x * 256 + threadIdx.x;     // [0, 32768)
    {   // internal AB, swizzled columns
        int jh = idx >> 14, rest = idx & 16383;
        int P = rest >> 7, jcol = rest & 127;
        int j = jcol ^ (((P >> 3) & 7) << 1);
        int jg = (jh << 7) + j;
        int i0 = 2 * P, i1 = i0 + 1;
        unsigned a0 = f2h(-isig[i0 * H_ + jg] * K);
        unsigned a1 = f2h(-isig[i1 * H_ + jg] * K);
        unsigned b0 = f2h(isig[i0 * H_ + jg] * imu[i0 * H_ + jg] * K);
        unsigned b1 = f2h(isig[i1 * H_ + jg] * imu[i1 * H_ + jg] * K);
        ABg[idx] = make_uint2(a0 | (a1 << 16), b0 | (b1 << 16));
    }
    {   // internal W [P][jg]
        int P = idx >> 8, jg = idx & 255;
        int i0 = 2 * P, i1 = i0 + 1;
        unsigned w0 = f2h(iw[i0 * H_ + jg] * ierev[i0 * H_ + jg]);
        unsigned w1 = f2h(iw[i1 * H_ + jg] * ierev[i1 * H_ + jg]);
        Wg[idx] = w0 | (w1 << 16);
    }
    if (idx < 64 * H_) {   // sensing [p][jg]
        int p = idx >> 8, jg = idx & 255;
        int i0 = 2 * p, i1 = i0 + 1;
        unsigned a0 = f2h(-ssig[i0 * H_ + jg] * K);
        unsigned a1 = f2h(-ssig[i1 * H_ + jg] * K);
        unsigned b0 = f2h(ssig[i0 * H_ + jg] * smu[i0 * H_ + jg] * K);
        unsigned b1 = f2h(ssig[i1 * H_ + jg] * smu[i1 * H_ + jg] * K);
        SABg[idx] = make_uint2(a0 | (a1 << 16), b0 | (b1 << 16));
        unsigned w0 = f2h(sw[i0 * H_ + jg] * serev[i0 * H_ + jg]);
        unsigned w1 = f2h(sw[i1 * H_ + jg] * serev[i1 * H_ + jg]);
        SWg[idx] = w0 | (w1 << 16);
    }
    Vg4[idx] = 0u;
    Vg4[idx + 32768] = 0u;
}

// ---------------- K1: recurrent LTC (R7 structure — proven best, 972 us).
// 2 blocks per batch (j-half each), 1 block/CU (131 KB LDS), all 256 co-resident.
// Lane map tid = j*8 + c; 8 partials per neuron reduce via shfl_xor in-wave.
// Internal A,B in LDS (XOR-swizzled, ds_read_b64); internal W register-cached
// (16 words, fits 64-VGPR alloc, no remat); sensing params streamed from L2
// once per t (amortized over 6 unfolds). Cross-block V via self-tagged relaxed
// agent atomics (tag<<16 | fp16(V)), double-buffered by unfold parity; waves
// 0-1 poll (1 word/lane), prefetch issued before phase A so the L2 RT hides
// under gate compute. 2 barriers per unfold.
__global__ __launch_bounds__(1024)
__attribute__((amdgpu_waves_per_eu(4, 4)))
void ltc_rec(
    const float* __restrict__ x, const float* __restrict__ in_w, const float* __restrict__ in_b,
    const uint2* __restrict__ ABg, const unsigned* __restrict__ Wg,
    const uint2* __restrict__ SABg, const unsigned* __restrict__ SWg,
    const float* __restrict__ vleak, const float* __restrict__ gleak, const float* __restrict__ cm,
    const float* __restrict__ out_w, const float* __restrict__ out_b,
    unsigned* __restrict__ Vg4,
    float* __restrict__ out, float* __restrict__ hT)
{
    // LDS: [0, 131072) AB params | V2u (512 B) | xs2 (256 B)
    __shared__ __align__(16) unsigned char L[131840];
    unsigned* V2u = (unsigned*)(L + 131072);
    unsigned* xs2 = (unsigned*)(L + 131584);

    const int bx  = blockIdx.x;
    const int b   = bx & 127;
    const int jh  = bx >> 7;
    const int tid = threadIdx.x;
    const int c   = tid & 7;
    const int j   = tid >> 3;
    const int jg  = (jh << 7) + j;
    const int pjbase = (jh ^ 1) << 7;
    const int BH  = B_ * H_;

    // stage internal AB (own column-half, pre-swizzled) into LDS: 128 KB
    {
        const uint4* src = (const uint4*)(ABg + ((size_t)jh << 14));
        uint4* dst = (uint4*)L;
        #pragma unroll
        for (int k = 0; k < 8; ++k) dst[tid + (k << 10)] = src[tid + (k << 10)];
    }

    // internal W registers: 8 own + 8 peer pairs
    unsigned rw[16];
    {
        const int po = (jh << 6) + (c << 3);
        const int pp = ((jh ^ 1) << 6) + (c << 3);
        #pragma unroll
        for (int k = 0; k < 8; ++k) {
            rw[k]     = Wg[((po + k) << 8) + jg];
            rw[8 + k] = Wg[((pp + k) << 8) + jg];
        }
    }

    const float cmt  = cm[jg] * (float)UF;
    const float gl   = gleak[jg];
    const float glvl = gl * vleak[jg];
    const float dc   = cmt + gl + EPSF;
    const float owj  = out_w[jg], obj = out_b[jg];
    float iw0 = 0.f, iw1 = 0.f, ib0 = 0.f, ib1 = 0.f;
    if (tid < 64) { iw0 = in_w[2 * tid]; iw1 = in_w[2 * tid + 1];
                    ib0 = in_b[2 * tid]; ib1 = in_b[2 * tid + 1]; }
    if (tid < 128) V2u[tid] = 0u;
    float vreg = 0.f;

    const float* xrow = x + (size_t)b * (T_ * I_);

    const int colb = (j ^ (c << 1)) << 3;   // swizzled column byte offset
    const char* abA = (const char*)L + ((((jh << 6) + (c << 3))) << 10) + colb;
    const char* abB = (const char*)L + (((((jh ^ 1) << 6)) + (c << 3)) << 10) + colb;
    const int vbaseA = (jh << 6) + (c << 3);
    const int vbaseB = ((jh ^ 1) << 6) + (c << 3);
    const uint2* sabBase = SABg + ((c << 3) << 8) + jg;
    const unsigned* swBase = SWg + ((c << 3) << 8) + jg;

    for (int t = 0; t < T_; ++t) {
        if (tid < 64) {
            float2 xv = *(const float2*)(xrow + t * I_ + 2 * tid);
            H2U u_; u_.h = __floats2half2_rn(fmaf(xv.x, iw0, ib0), fmaf(xv.y, iw1, ib1));
            xs2[tid] = u_.u;
        }
        __syncthreads();   // xs2 ready (covers AB/V2u init at t==0)

        // ---- sensing partials: params streamed from L2, reused for 6 unfolds
        float qsn = 0.f, qsd = 0.f;
        {
            const uint4 xa = *(const uint4*)(xs2 + (c << 3));
            const uint4 xb = *(const uint4*)(xs2 + (c << 3) + 4);
            #pragma unroll
            for (int k = 0; k < 8; ++k) {
                uint2 sab = sabBase[k << 8];
                unsigned swv = swBase[k << 8];
                unsigned xw = (k < 4) ? ((const unsigned*)&xa)[k] : ((const unsigned*)&xb)[k - 4];
                GATE2(xw, sab.x, sab.y, swv, qsn, qsd);
            }
        }

        for (int u = 0; u < UF; ++u) {
            const int p = t * UF + u + 1;
            float nm = qsn, dn = qsd;

            // prefetch peer V(p-1): issue load now, check after phase A
            unsigned pv = 0; const unsigned* src = nullptr; unsigned want = 0;
            if (p > 1 && tid < 128) {
                want = (unsigned)(p - 1);
                src = Vg4 + (size_t)(want & 1) * BH + (b << 8) + pjbase + tid;
                pv = __hip_atomic_load(src, __ATOMIC_RELAXED, __HIP_MEMORY_SCOPE_AGENT);
            }

            // ---- phase A: own-half source pairs (AB from LDS)
            {
                const uint4 va = *(const uint4*)(V2u + vbaseA);
                const uint4 vb = *(const uint4*)(V2u + vbaseA + 4);
                #pragma unroll
                for (int k = 0; k < 8; ++k) {
                    uint2 ab = *(const uint2*)(abA + (k << 10));
                    unsigned vw = (k < 4) ? ((const unsigned*)&va)[k] : ((const unsigned*)&vb)[k - 4];
                    GATE2(vw, ab.x, ab.y, rw[k], nm, dn);
                }
            }

            // ---- waves 0-1: finish poll, write peer V2u region
            if (p > 1 && tid < 128) {
                while ((pv >> 16) != want)
                    pv = __hip_atomic_load(src, __ATOMIC_RELAXED, __HIP_MEMORY_SCOPE_AGENT);
                unsigned hv = pv & 0xffffu;
                unsigned hv1 = (unsigned)__shfl_down((int)hv, 1);
                if (!(tid & 1)) V2u[(pjbase >> 1) + (tid >> 1)] = hv | (hv1 << 16);
            }
            __syncthreads();   // peer V2u ready

            // ---- phase B: peer-half source pairs
            {
                const uint4 va = *(const uint4*)(V2u + vbaseB);
                const uint4 vb = *(const uint4*)(V2u + vbaseB + 4);
                #pragma unroll
                for (int k = 0; k < 8; ++k) {
                    uint2 ab = *(const uint2*)(abB + (k << 10));
                    unsigned vw = (k < 4) ? ((const unsigned*)&va)[k] : ((const unsigned*)&vb)[k - 4];
                    GATE2(vw, ab.x, ab.y, rw[8 + k], nm, dn);
                }
            }

            // ---- in-wave reduce over c
            nm += __shfl_xor(nm, 1); dn += __shfl_xor(dn, 1);
            nm += __shfl_xor(nm, 2); dn += __shfl_xor(dn, 2);
            nm += __shfl_xor(nm, 4); dn += __shfl_xor(dn, 4);

            // ---- update (all lanes), publish + own V2u write
            float Vn = (fmaf(vreg, cmt, glvl) + nm) * rcpf(dn + dc);
            vreg = Vn;
            unsigned h0 = (unsigned)__half_as_ushort(__float2half_rn(Vn));
            if (c == 0)
                __hip_atomic_store(Vg4 + (size_t)(p & 1) * BH + (b << 8) + jg,
                                   ((unsigned)p << 16) | h0,
                                   __ATOMIC_RELAXED, __HIP_MEMORY_SCOPE_AGENT);
            unsigned h1 = (unsigned)__shfl_down((int)h0, 8);
            if (c == 0 && !(j & 1)) V2u[jg >> 1] = h0 | (h1 << 16);
            __syncthreads();   // own V2u ready for next phase A
        }

        if (c == 0) out[((size_t)b * T_ + t) * H_ + jg] = fmaf(vreg, owj, obj);
    }
    if (c == 0) hT[(b << 8) + jg] = vreg;
}

extern "C" void kernel_launch(void* const* d_in, const int* in_sizes, int n_in,
                              void* d_out, int out_size, void* d_ws, size_t ws_size,
                              hipStream_t stream) {
    const float* x     = (const float*)d_in[0];
    const float* in_w  = (const float*)d_in[1];
    const float* in_b  = (const float*)d_in[2];
    const float* smu   = (const float*)d_in[3];
    const float* ssig  = (const float*)d_in[4];
    const float* sw    = (const float*)d_in[5];
    const float* serev = (const float*)d_in[6];
    const float* imu   = (const float*)d_in[7];
    const float* isig  = (const float*)d_in[8];
    const float* iw    = (const float*)d_in[9];
    const float* ierev = (const float*)d_in[10];
    const float* vleak = (const float*)d_in[11];
    const float* gleak = (const float*)d_in[12];
    const float* cmv   = (const float*)d_in[13];
    const float* ow    = (const float*)d_in[14];
    const float* ob    = (const float*)d_in[15];

    float* out = (float*)d_out;                 // [B, T, H]
    float* hT  = out + (size_t)B_ * T_ * H_;    // [B, H]

    char* w = (char*)d_ws;
    uint2*    ABg  = (uint2*)(w);                    // 256 KB [jh][P][jcol] swizzled
    unsigned* Wg   = (unsigned*)(w + (256 << 10));   // 128 KB [P][jg]
    uint2*    SABg = (uint2*)(w + (384 << 10));      // 128 KB [p][jg]
    unsigned* SWg  = (unsigned*)(w + (512 << 10));   //  64 KB [p][jg]
    unsigned* Vg4  = (unsigned*)(w + (576 << 10));   // 256 KB [2][B][H] tag|fp16

    pack_params<<<dim3(128), dim3(256), 0, stream>>>(
        smu, ssig, sw, serev, imu, isig, iw, ierev, ABg, Wg, SABg, SWg, Vg4);

    ltc_rec<<<dim3(256), dim3(1024), 0, stream>>>(
        x, in_w, in_b, ABg, Wg, SABg, SWg, vleak, gleak, cmv, ow, ob,
        Vg4, out, hT);
}